// Round 18
// baseline (119.757 us; speedup 1.0000x reference)
//
#include <hip/hip_runtime.h>
#include <hip/hip_bf16.h>

#define SVOL 110592   // 48*48*48 voxels
#define HD   2304     // 48*48
#define NDIM 48

typedef __attribute__((ext_vector_type(4))) float f32x4;
typedef __attribute__((ext_vector_type(8))) short bf16x8;
typedef __attribute__((ext_vector_type(2))) unsigned int u32x2;
typedef unsigned short ushort_t;
typedef unsigned int uint_t;

// ---------------- Kernel 0: W fp32 -> bf16 ----------------
__global__ __launch_bounds__(256) void wconv_kernel(const float* __restrict__ W,
                                                    ushort_t* __restrict__ Wb) {
    int i = blockIdx.x * 256 + threadIdx.x;   // 128*256 = 32768 exactly
    float f = W[i];
    __hip_bfloat16 h = __float2bfloat16(f);
    Wb[i] = *(ushort_t*)&h;
}

// ---------------- Kernel 1: parity-min tables via LDS-staged plane quads ----------------
// tabDp[part][bc][p][h*48+w] (partial), tabH[bc][p][d*48+w], tabW[bc][p][d*48+h]
__global__ __launch_bounds__(256) void tables_kernel(const float* __restrict__ x,
                                                     float* __restrict__ tabDp,
                                                     float* __restrict__ tabH,
                                                     float* __restrict__ tabW) {
    __shared__ __align__(16) float sl[4 * HD];   // 36 KB: 4 planes, linear
    const int bc   = blockIdx.x;
    const int part = blockIdx.y;     // 0..2
    const float* __restrict__ xp = x + (size_t)bc * SVOL + (size_t)part * 16 * HD;
    const int t    = threadIdx.x;
    const int w4   = t >> 6;         // wave 0..3
    const int lane = t & 63;
    const int dlh  = t / NDIM;       // H/W task split (t < 192): plane-local d
    const int wh   = t - dlh * NDIM; // 0..47

    f32x4 accD[3][2];
    #pragma unroll
    for (int s = 0; s < 3; ++s)
        #pragma unroll
        for (int p = 0; p < 2; ++p)
            #pragma unroll
            for (int e = 0; e < 4; ++e) accD[s][p][e] = 3e38f;

    for (int q = 0; q < 4; ++q) {
        const float* __restrict__ qp = xp + (size_t)q * 4 * HD;
        #pragma unroll
        for (int k = 0; k < 9; ++k) {
            const int i16 = (k * 4 + w4) * 64 + lane;
            __builtin_amdgcn_global_load_lds(
                (const __attribute__((address_space(1))) void*)(qp + (size_t)i16 * 4),
                (__attribute__((address_space(3))) void*)&sl[(k * 4 + w4) * 256],
                16, 0, 0);
        }
        __syncthreads();

        #pragma unroll
        for (int s = 0; s < 3; ++s) {
            const int j = t + s * 256;
            if (j < 576) {
                #pragma unroll
                for (int dl = 0; dl < 4; ++dl) {
                    f32x4 v = ((const f32x4*)sl)[dl * 576 + j];
                    #pragma unroll
                    for (int e = 0; e < 4; ++e)
                        accD[s][dl & 1][e] = fminf(accD[s][dl & 1][e], v[e]);
                }
            }
        }
        if (t < 192) {
            const int d = part * 16 + q * 4 + dlh;
            {   // H: min over h at fixed (dlh, w=wh)
                const float* pb = sl + dlh * HD + wh;
                float m0 = 3e38f, m1 = 3e38f;
                #pragma unroll
                for (int h = 0; h < NDIM; h += 2) {
                    m0 = fminf(m0, pb[h * NDIM]);
                    m1 = fminf(m1, pb[(h + 1) * NDIM]);
                }
                tabH[(size_t)bc * 2 * HD + d * NDIM + wh]      = m0;
                tabH[(size_t)bc * 2 * HD + HD + d * NDIM + wh] = m1;
            }
            {   // W: min over w at fixed (dlh, h=wh)
                const f32x4* pr = (const f32x4*)(sl + dlh * HD + wh * NDIM);
                const int rot = wh % 12;
                float m0 = 3e38f, m1 = 3e38f;
                #pragma unroll
                for (int j = 0; j < 12; ++j) {
                    int jj = j + rot; if (jj >= 12) jj -= 12;
                    f32x4 v = pr[jj];
                    m0 = fminf(m0, fminf(v[0], v[2]));
                    m1 = fminf(m1, fminf(v[1], v[3]));
                }
                tabW[(size_t)bc * 2 * HD + d * NDIM + wh]      = m0;
                tabW[(size_t)bc * 2 * HD + HD + d * NDIM + wh] = m1;
            }
        }
        __syncthreads();
    }

    float* tDo = tabDp + ((size_t)part * 256 + bc) * 2 * HD;
    #pragma unroll
    for (int s = 0; s < 3; ++s) {
        const int j = t + s * 256;
        if (j < 576) {
            *((f32x4*)(tDo + j * 4))      = accD[s][0];
            *((f32x4*)(tDo + HD + j * 4)) = accD[s][1];
        }
    }
}

// ---------------- Kernel 2: merge 3 tabD partials -> tabD ----------------
__global__ __launch_bounds__(256) void merge_kernel(const float* __restrict__ tabDp,
                                                    float* __restrict__ tabD) {
    const int i = blockIdx.x * 256 + threadIdx.x;    // f32x4 id, 294912 total
    f32x4 a  = ((const f32x4*)tabDp)[i];
    f32x4 d1 = ((const f32x4*)(tabDp + (size_t)256 * 2 * HD))[i];
    f32x4 d2 = ((const f32x4*)(tabDp + (size_t)2 * 256 * 2 * HD))[i];
    f32x4 m;
    #pragma unroll
    for (int j = 0; j < 4; ++j) m[j] = fminf(a[j], fminf(d1[j], d2[j]));
    ((f32x4*)tabD)[i] = m;
}

// ---------------- Kernel 3: fused xj + GEMM (R17 shell, 16-read tr phases) ----------------
// Tile 128o x 64s; LDS 32 KB single buffer; TPB=2 (grid 1728 = 6.75/CU).
// Register diet: tr_reads in 4 phases of 16 (lo/hi[2][4] = 32 VGPR, was 64) so
// total/wave (VGPR + 32 acc-AGPR, unified file on gfx950) fits ~5 waves/SIMD.
// NO launch_bounds min-waves: R9/R10 proved forcing the allocator causes
// +100 MB/way scratch spill; take the natural allocation.
#define TPB 2
__global__ __launch_bounds__(256) void gemm_kernel(const float* __restrict__ x,
                                                   const float* __restrict__ tabD,
                                                   const float* __restrict__ tabH,
                                                   const float* __restrict__ tabW,
                                                   const ushort_t* __restrict__ Wb,
                                                   const float* __restrict__ bias,
                                                   float* __restrict__ out) {
    __shared__ __align__(1024) ushort_t ytile[16384];   // 32 KB
    const int tile0 = blockIdx.x * TPB;
    const int b  = blockIdx.y;
    const int t  = threadIdx.x;
    const int wid = t >> 6, lane = t & 63;   // 4 waves
    const int row  = lane & 3;               // c & 3
    const int colq = (lane >> 2) & 3;        // col quad
    const int sqq  = (lane >> 4) & 3;        // sq
    const int sloc = (sqq * 4 + colq) * 4;   // s within tile, mult of 4
    const int l15 = lane & 15, l4 = lane >> 4;

    const float* __restrict__ xb = x + (size_t)b * 128 * SVOL;
    const size_t tbb = (size_t)b * 128 * 2 * HD;   // table base for this b

    const ushort_t* wp = Wb + (size_t)(wid * 32 + l15) * 256 + l4 * 8;
    float bv[2];
    #pragma unroll
    for (int m = 0; m < 2; ++m) bv[m] = bias[wid * 32 + m * 16 + l15];

    // plane geometry: constant per block (TPB*64 = 128 divides HD = 2304)
    const int d  = (tile0 * 64) / HD;
    const int rb = tile0 * 64 - d * HD;      // r of tile0's first voxel
    const int pd = d & 1;

    uint2 pk[8][2];
    auto stage = [&](int tile) {
        const int r  = rb + (tile - tile0) * 64 + sloc;   // this thread's r, mult of 4
        const int h  = r / NDIM;
        const int w0 = r - h * NDIM;
        const int ph = h & 1;
        const int s  = d * HD + r;
        #pragma unroll
        for (int it = 0; it < 8; ++it) {
            const int c = (it * 4 + wid) * 4 + row;
            const size_t tb = tbb + (size_t)c * 2 * HD;
            f32x4 xv = *(const f32x4*)(xb + (size_t)c * SVOL + s);
            f32x4 mD = *(const f32x4*)(tabD + tb + pd * HD + r);
            f32x4 mH = *(const f32x4*)(tabH + tb + ph * HD + d * NDIM + w0);
            const float mW0 = tabW[tb + d * NDIM + h];
            const float mW1 = tabW[tb + HD + d * NDIM + h];
            union { __hip_bfloat16 h4[4]; uint2 u; } ox, oj;
            #pragma unroll
            for (int j = 0; j < 4; ++j) {
                const float mm = fminf(mD[j], fminf(mH[j], (j & 1) ? mW1 : mW0));
                ox.h4[j] = __float2bfloat16(xv[j]);
                oj.h4[j] = __float2bfloat16(fmaxf(0.0f, xv[j] - mm));
            }
            pk[it][0] = ox.u; pk[it][1] = oj.u;
        }
    };

    const uint_t lds_base = (uint_t)(uintptr_t)(__attribute__((address_space(3))) ushort_t*)&ytile[0];
    float* ob = out + (size_t)b * 128 * SVOL;

    stage(tile0);

    #pragma unroll
    for (int tt = 0; tt < TPB; ++tt) {
        __syncthreads();                       // all waves done reading previous tile
        {
            #pragma unroll
            for (int it = 0; it < 8; ++it) {
                const int A = (it * 4 + wid) * 512 + sqq * 128 + row * 32 + colq * 8;
                *(uint2*)&ytile[A >> 1]             = pk[it][0];   // x part (cq 0..31)
                *(uint2*)&ytile[(A + 16384) >> 1]   = pk[it][1];   // xj part (cq 32..63)
            }
        }
        __syncthreads();                       // tile tt staged for all waves

        const uint_t addrB = lds_base + (uint_t)(l4 * 1024 + l15 * 8);
        f32x4 acc[4][2] = {};
        #pragma unroll
        for (int ph4 = 0; ph4 < 4; ++ph4) {    // 4 phases x 16 tr_reads (pressure cap)
            u32x2 lo[2][4], hi[2][4];
            #pragma unroll
            for (int kk = 0; kk < 2; ++kk)
                #pragma unroll
                for (int n = 0; n < 4; ++n) {
                    const uint_t ad = addrB + (uint_t)((ph4 * 2 + kk) * 4096 + n * 128);
                    asm volatile("ds_read_b64_tr_b16 %0, %2 offset:0\n\t"
                                 "ds_read_b64_tr_b16 %1, %2 offset:512"
                                 : "=&v"(lo[kk][n]), "=&v"(hi[kk][n]) : "v"(ad) : "memory");
                }
            asm volatile("s_waitcnt lgkmcnt(0)" ::: "memory");
            __builtin_amdgcn_sched_barrier(0);
            #pragma unroll
            for (int kk = 0; kk < 2; ++kk) {
                bf16x8 aw[2];
                #pragma unroll
                for (int m = 0; m < 2; ++m)
                    aw[m] = *(const bf16x8*)(wp + ((size_t)m * 16 * 256 + (ph4 * 2 + kk) * 32));
                #pragma unroll
                for (int n = 0; n < 4; ++n) {
                    union { u32x2 u2[2]; bf16x8 v; } cvt;
                    cvt.u2[0] = lo[kk][n]; cvt.u2[1] = hi[kk][n];
                    #pragma unroll
                    for (int m = 0; m < 2; ++m)   // swapped operands: D rows = s
                        acc[n][m] = __builtin_amdgcn_mfma_f32_16x16x32_bf16(cvt.v, aw[m], acc[n][m], 0, 0, 0);
                }
            }
        }

        // Stage the NEXT tile here: pk only lives across stores + loop backedge;
        // its load latency hides under stores/barrier + resident blocks.
        if (tt + 1 < TPB) stage(tile0 + tt + 1);

        const int s_b = (tile0 + tt) * 64;
        #pragma unroll
        for (int n = 0; n < 4; ++n)
            #pragma unroll
            for (int m = 0; m < 2; ++m) {
                const int o = wid * 32 + m * 16 + l15;
                const int s = s_b + n * 16 + l4 * 4;
                f32x4 r;
                #pragma unroll
                for (int j = 0; j < 4; ++j) r[j] = fmaxf(acc[n][m][j] + bv[m], 0.0f);
                *(f32x4*)(ob + (size_t)o * SVOL + s) = r;
            }
    }
}

extern "C" void kernel_launch(void* const* d_in, const int* in_sizes, int n_in,
                              void* d_out, int out_size, void* d_ws, size_t ws_size,
                              hipStream_t stream) {
    const float* x    = (const float*)d_in[0];
    const float* W    = (const float*)d_in[1];
    const float* bias = (const float*)d_in[2];
    float* out = (float*)d_out;

    // d_ws layout: Wb (64 KB) | tabDp (13.5 MB) | tabH (4.5) | tabW (4.5) | tabD (4.5)
    ushort_t* Wb   = (ushort_t*)d_ws;
    float* tabDp = (float*)((char*)d_ws + 65536);
    float* tabH  = tabDp + (size_t)3 * 256 * 2 * HD;
    float* tabW  = tabH  + (size_t)256 * 2 * HD;
    float* tabD  = tabW  + (size_t)256 * 2 * HD;

    wconv_kernel<<<128, 256, 0, stream>>>(W, Wb);
    tables_kernel<<<dim3(256, 3), 256, 0, stream>>>(x, tabDp, tabH, tabW);
    merge_kernel<<<1152, 256, 0, stream>>>(tabDp, tabD);
    gemm_kernel<<<dim3(SVOL / 64 / TPB, 2), 256, 0, stream>>>(x, tabD, tabH, tabW, Wb, bias, out);
}

// Round 20
// 113.212 us; speedup vs baseline: 1.0578x; 1.0578x over previous
//
#include <hip/hip_runtime.h>
#include <hip/hip_bf16.h>

#define SVOL 110592   // 48*48*48 voxels
#define HD   2304     // 48*48
#define NDIM 48

typedef __attribute__((ext_vector_type(4))) float f32x4;
typedef __attribute__((ext_vector_type(8))) short bf16x8;
typedef __attribute__((ext_vector_type(2))) unsigned int u32x2;
typedef unsigned short ushort_t;
typedef unsigned int uint_t;

__device__ __forceinline__ ushort_t f2b(float f) {
    __hip_bfloat16 h = __float2bfloat16(f);
    return *(ushort_t*)&h;
}
__device__ __forceinline__ float b2f(uint_t u) {   // u = bf16 bits in low 16
    union { float f; uint_t i; } v; v.i = u << 16; return v.f;
}

// ---------------- Kernel 0: W fp32 -> bf16 ----------------
__global__ __launch_bounds__(256) void wconv_kernel(const float* __restrict__ W,
                                                    ushort_t* __restrict__ Wb) {
    int i = blockIdx.x * 256 + threadIdx.x;   // 128*256 = 32768 exactly
    Wb[i] = f2b(W[i]);
}

// ---------------- Kernel 1: parity-min tables (bf16 out) ----------------
// tabDp[part][bc][p][h*48+w] (partial), tabH[bc][p][d*48+w], tabW[bc][p][d*48+h]
__global__ __launch_bounds__(256) void tables_kernel(const float* __restrict__ x,
                                                     ushort_t* __restrict__ tabDp,
                                                     ushort_t* __restrict__ tabH,
                                                     ushort_t* __restrict__ tabW) {
    __shared__ __align__(16) float sl[4 * HD];   // 36 KB: 4 planes, linear
    const int bc   = blockIdx.x;
    const int part = blockIdx.y;     // 0..2
    const float* __restrict__ xp = x + (size_t)bc * SVOL + (size_t)part * 16 * HD;
    const int t    = threadIdx.x;
    const int w4   = t >> 6;         // wave 0..3
    const int lane = t & 63;
    const int dlh  = t / NDIM;       // H/W task split (t < 192): plane-local d
    const int wh   = t - dlh * NDIM; // 0..47

    f32x4 accD[3][2];
    #pragma unroll
    for (int s = 0; s < 3; ++s)
        #pragma unroll
        for (int p = 0; p < 2; ++p)
            #pragma unroll
            for (int e = 0; e < 4; ++e) accD[s][p][e] = 3e38f;

    for (int q = 0; q < 4; ++q) {
        const float* __restrict__ qp = xp + (size_t)q * 4 * HD;
        #pragma unroll
        for (int k = 0; k < 9; ++k) {
            const int i16 = (k * 4 + w4) * 64 + lane;
            __builtin_amdgcn_global_load_lds(
                (const __attribute__((address_space(1))) void*)(qp + (size_t)i16 * 4),
                (__attribute__((address_space(3))) void*)&sl[(k * 4 + w4) * 256],
                16, 0, 0);
        }
        __syncthreads();

        #pragma unroll
        for (int s = 0; s < 3; ++s) {
            const int j = t + s * 256;
            if (j < 576) {
                #pragma unroll
                for (int dl = 0; dl < 4; ++dl) {
                    f32x4 v = ((const f32x4*)sl)[dl * 576 + j];
                    #pragma unroll
                    for (int e = 0; e < 4; ++e)
                        accD[s][dl & 1][e] = fminf(accD[s][dl & 1][e], v[e]);
                }
            }
        }
        if (t < 192) {
            const int d = part * 16 + q * 4 + dlh;
            {   // H: min over h at fixed (dlh, w=wh)
                const float* pb = sl + dlh * HD + wh;
                float m0 = 3e38f, m1 = 3e38f;
                #pragma unroll
                for (int h = 0; h < NDIM; h += 2) {
                    m0 = fminf(m0, pb[h * NDIM]);
                    m1 = fminf(m1, pb[(h + 1) * NDIM]);
                }
                tabH[(size_t)bc * 2 * HD + d * NDIM + wh]      = f2b(m0);
                tabH[(size_t)bc * 2 * HD + HD + d * NDIM + wh] = f2b(m1);
            }
            {   // W: min over w at fixed (dlh, h=wh)
                const f32x4* pr = (const f32x4*)(sl + dlh * HD + wh * NDIM);
                const int rot = wh % 12;
                float m0 = 3e38f, m1 = 3e38f;
                #pragma unroll
                for (int j = 0; j < 12; ++j) {
                    int jj = j + rot; if (jj >= 12) jj -= 12;
                    f32x4 v = pr[jj];
                    m0 = fminf(m0, fminf(v[0], v[2]));
                    m1 = fminf(m1, fminf(v[1], v[3]));
                }
                tabW[(size_t)bc * 2 * HD + d * NDIM + wh]      = f2b(m0);
                tabW[(size_t)bc * 2 * HD + HD + d * NDIM + wh] = f2b(m1);
            }
        }
        __syncthreads();
    }

    ushort_t* tDo = tabDp + ((size_t)part * 256 + bc) * 2 * HD;
    #pragma unroll
    for (int s = 0; s < 3; ++s) {
        const int j = t + s * 256;
        if (j < 576) {
            union { ushort_t s4[4]; uint2 u; } p0, p1;
            #pragma unroll
            for (int e = 0; e < 4; ++e) { p0.s4[e] = f2b(accD[s][0][e]); p1.s4[e] = f2b(accD[s][1][e]); }
            *(uint2*)(tDo + j * 4)      = p0.u;
            *(uint2*)(tDo + HD + j * 4) = p1.u;
        }
    }
}

// ---------------- Kernel 2: merge 3 bf16 tabD partials -> tabD ----------------
__global__ __launch_bounds__(256) void merge_kernel(const ushort_t* __restrict__ tabDp,
                                                    ushort_t* __restrict__ tabD) {
    const int i = blockIdx.x * 256 + threadIdx.x;    // uint2 id, 294912 total
    const size_t off = (size_t)256 * 2 * HD / 4;     // partial stride in uint2
    union U { uint2 u; ushort_t s4[4]; } a, b1, c, o;
    a.u  = ((const uint2*)tabDp)[i];
    b1.u = ((const uint2*)tabDp)[i + off];
    c.u  = ((const uint2*)tabDp)[i + 2 * off];
    #pragma unroll
    for (int j = 0; j < 4; ++j)
        o.s4[j] = f2b(fminf(b2f(a.s4[j]), fminf(b2f(b1.s4[j]), b2f(c.s4[j]))));
    ((uint2*)tabD)[i] = o.u;
}

// ---------------- Kernel 3: fused xj + GEMM (R18 grid shape, bf16 tables, in-x XCD swizzle) ----------------
// Tile 128o x 64s; LDS 32 KB single buffer; TPB=2; grid dim3(864,2) -> x
// swizzled (bx&7)*108+(bx>>3)... NOTE: x-dim = 1728/TPB = 864 = 8*108 exact.
#define TPB 2
__global__ __launch_bounds__(256) void gemm_kernel(const float* __restrict__ x,
                                                   const ushort_t* __restrict__ tabD,
                                                   const ushort_t* __restrict__ tabH,
                                                   const ushort_t* __restrict__ tabW,
                                                   const ushort_t* __restrict__ Wb,
                                                   const float* __restrict__ bias,
                                                   float* __restrict__ out) {
    __shared__ __align__(1024) ushort_t ytile[16384];   // 32 KB
    const int bx  = blockIdx.x;                   // 0..863
    const int b   = blockIdx.y;
    const int swz = (bx & 7) * 108 + (bx >> 3);   // bijective: 864 = 8*108
    const int tile0 = swz * TPB;
    const int t  = threadIdx.x;
    const int wid = t >> 6, lane = t & 63;   // 4 waves
    const int row  = lane & 3;               // c & 3
    const int colq = (lane >> 2) & 3;        // col quad
    const int sqq  = (lane >> 4) & 3;        // sq
    const int sloc = (sqq * 4 + colq) * 4;   // s within tile, mult of 4
    const int l15 = lane & 15, l4 = lane >> 4;

    const float* __restrict__ xb = x + (size_t)b * 128 * SVOL;
    const size_t tbb = (size_t)b * 128 * 2 * HD;   // table base (ushort units)

    const ushort_t* wp = Wb + (size_t)(wid * 32 + l15) * 256 + l4 * 8;
    float bv[2];
    #pragma unroll
    for (int m = 0; m < 2; ++m) bv[m] = bias[wid * 32 + m * 16 + l15];

    // plane geometry: constant per block (TPB*64 = 128 divides HD = 2304)
    const int d  = (tile0 * 64) / HD;
    const int rb = tile0 * 64 - d * HD;      // r of tile0's first voxel
    const int pd = d & 1;

    uint2 pk[8][2];
    auto stage = [&](int tile) {
        const int r  = rb + (tile - tile0) * 64 + sloc;   // this thread's r, mult of 4
        const int h  = r / NDIM;
        const int w0 = r - h * NDIM;
        const int ph = h & 1;
        const int s  = d * HD + r;
        #pragma unroll
        for (int it = 0; it < 8; ++it) {
            const int c = (it * 4 + wid) * 4 + row;
            const size_t tb = tbb + (size_t)c * 2 * HD;
            f32x4 xv = *(const f32x4*)(xb + (size_t)c * SVOL + s);
            uint2 md2 = *(const uint2*)(tabD + tb + pd * HD + r);
            uint2 mh2 = *(const uint2*)(tabH + tb + ph * HD + d * NDIM + w0);
            const float mW0 = b2f(tabW[tb + d * NDIM + h]);
            const float mW1 = b2f(tabW[tb + HD + d * NDIM + h]);
            float mD[4] = { b2f(md2.x & 0xffffu), b2f(md2.x >> 16),
                            b2f(md2.y & 0xffffu), b2f(md2.y >> 16) };
            float mH[4] = { b2f(mh2.x & 0xffffu), b2f(mh2.x >> 16),
                            b2f(mh2.y & 0xffffu), b2f(mh2.y >> 16) };
            union { __hip_bfloat16 h4[4]; uint2 u; } ox, oj;
            #pragma unroll
            for (int j = 0; j < 4; ++j) {
                const float mm = fminf(mD[j], fminf(mH[j], (j & 1) ? mW1 : mW0));
                ox.h4[j] = __float2bfloat16(xv[j]);
                oj.h4[j] = __float2bfloat16(fmaxf(0.0f, xv[j] - mm));
            }
            pk[it][0] = ox.u; pk[it][1] = oj.u;
        }
    };

    const uint_t lds_base = (uint_t)(uintptr_t)(__attribute__((address_space(3))) ushort_t*)&ytile[0];
    float* ob = out + (size_t)b * 128 * SVOL;

    stage(tile0);

    #pragma unroll
    for (int tt = 0; tt < TPB; ++tt) {
        __syncthreads();                       // all waves done reading previous tile
        {
            #pragma unroll
            for (int it = 0; it < 8; ++it) {
                const int A = (it * 4 + wid) * 512 + sqq * 128 + row * 32 + colq * 8;
                *(uint2*)&ytile[A >> 1]             = pk[it][0];   // x part (cq 0..31)
                *(uint2*)&ytile[(A + 16384) >> 1]   = pk[it][1];   // xj part (cq 32..63)
            }
        }
        __syncthreads();                       // tile tt staged for all waves

        const uint_t addrB = lds_base + (uint_t)(l4 * 1024 + l15 * 8);
        f32x4 acc[4][2] = {};
        #pragma unroll
        for (int ph4 = 0; ph4 < 4; ++ph4) {    // 4 phases x 16 tr_reads
            u32x2 lo[2][4], hi[2][4];
            #pragma unroll
            for (int kk = 0; kk < 2; ++kk)
                #pragma unroll
                for (int n = 0; n < 4; ++n) {
                    const uint_t ad = addrB + (uint_t)((ph4 * 2 + kk) * 4096 + n * 128);
                    asm volatile("ds_read_b64_tr_b16 %0, %2 offset:0\n\t"
                                 "ds_read_b64_tr_b16 %1, %2 offset:512"
                                 : "=&v"(lo[kk][n]), "=&v"(hi[kk][n]) : "v"(ad) : "memory");
                }
            asm volatile("s_waitcnt lgkmcnt(0)" ::: "memory");
            __builtin_amdgcn_sched_barrier(0);
            #pragma unroll
            for (int kk = 0; kk < 2; ++kk) {
                bf16x8 aw[2];
                #pragma unroll
                for (int m = 0; m < 2; ++m)
                    aw[m] = *(const bf16x8*)(wp + ((size_t)m * 16 * 256 + (ph4 * 2 + kk) * 32));
                #pragma unroll
                for (int n = 0; n < 4; ++n) {
                    union { u32x2 u2[2]; bf16x8 v; } cvt;
                    cvt.u2[0] = lo[kk][n]; cvt.u2[1] = hi[kk][n];
                    #pragma unroll
                    for (int m = 0; m < 2; ++m)   // swapped operands: D rows = s
                        acc[n][m] = __builtin_amdgcn_mfma_f32_16x16x32_bf16(cvt.v, aw[m], acc[n][m], 0, 0, 0);
                }
            }
        }

        // Stage the NEXT tile here: pk only lives across stores + loop backedge.
        if (tt + 1 < TPB) stage(tile0 + tt + 1);

        const int s_b = (tile0 + tt) * 64;
        #pragma unroll
        for (int n = 0; n < 4; ++n)
            #pragma unroll
            for (int m = 0; m < 2; ++m) {
                const int o = wid * 32 + m * 16 + l15;
                const int s = s_b + n * 16 + l4 * 4;
                f32x4 r;
                #pragma unroll
                for (int j = 0; j < 4; ++j) r[j] = fmaxf(acc[n][m][j] + bv[m], 0.0f);
                *(f32x4*)(ob + (size_t)o * SVOL + s) = r;
            }
    }
}

extern "C" void kernel_launch(void* const* d_in, const int* in_sizes, int n_in,
                              void* d_out, int out_size, void* d_ws, size_t ws_size,
                              hipStream_t stream) {
    const float* x    = (const float*)d_in[0];
    const float* W    = (const float*)d_in[1];
    const float* bias = (const float*)d_in[2];
    float* out = (float*)d_out;

    // d_ws (all bf16): Wb 64 KB | tabDp 6.75 MB | tabH 2.25 | tabW 2.25 | tabD 2.25
    ushort_t* Wb    = (ushort_t*)d_ws;
    ushort_t* tabDp = (ushort_t*)((char*)d_ws + 65536);
    ushort_t* tabH  = tabDp + (size_t)3 * 256 * 2 * HD;
    ushort_t* tabW  = tabH  + (size_t)256 * 2 * HD;
    ushort_t* tabD  = tabW  + (size_t)256 * 2 * HD;

    wconv_kernel<<<128, 256, 0, stream>>>(W, Wb);
    tables_kernel<<<dim3(256, 3), 256, 0, stream>>>(x, tabDp, tabH, tabW);
    merge_kernel<<<1152, 256, 0, stream>>>(tabDp, tabD);
    gemm_kernel<<<dim3(864, 2), 256, 0, stream>>>(x, tabD, tabH, tabW, Wb, bias, out);
}